// Round 9
// baseline (147.197 us; speedup 1.0000x reference)
//
#include <hip/hip_runtime.h>
#include <hip/hip_bf16.h>

#define GN 10000
#define GE 160000
#define GH 4
#define GD 128
#define GHD 512
#define GB 64
#define GC 2
#define GFF 768
#define SLOPE 0.2f

typedef __attribute__((ext_vector_type(8))) short bf16x8;
typedef __attribute__((ext_vector_type(4))) float f32x4;

__device__ __forceinline__ float leaky(float x) { return x >= 0.0f ? x : SLOPE * x; }

__device__ __forceinline__ unsigned short bf16_rne(float f) {
    unsigned u = __float_as_uint(f);
    u += 0x7fffu + ((u >> 16) & 1u);
    return (unsigned short)(u >> 16);
}
__device__ __forceinline__ float bf_lo(unsigned u) { return __uint_as_float(u << 16); }
__device__ __forceinline__ float bf_hi(unsigned u) { return __uint_as_float(u & 0xffff0000u); }

// ---------------- fused prep: conv_bf16 (625) | prep_w1 (32) | prep_w2 (32) | hist (625)
__global__ __launch_bounds__(256) void prep_misc(const float* __restrict__ x,
                                                 unsigned short* __restrict__ xb,
                                                 const float* __restrict__ W1,
                                                 short* __restrict__ w1s,
                                                 const float* __restrict__ W2,
                                                 short* __restrict__ w2s,
                                                 const int* __restrict__ dst,
                                                 int* __restrict__ deg) {
    const int b = blockIdx.x, t = threadIdx.x;
    if (b < 625) {
        const int i = b * 256 + t;
        const float4 a = ((const float4*)x)[i * 2];
        const float4 c = ((const float4*)x)[i * 2 + 1];
        ushort o[8] = {bf16_rne(a.x), bf16_rne(a.y), bf16_rne(a.z), bf16_rne(a.w),
                       bf16_rne(c.x), bf16_rne(c.y), bf16_rne(c.z), bf16_rne(c.w)};
        ((uint4*)xb)[i] = *(const uint4*)o;
    } else if (b < 689) {
        // W [128,512] f32 -> B-fragment bf16: [ct(32)][kt(4)][lane(64)][8]
        // lane l, reg j -> B[k=kt*32+(l>>4)*8+j][col=ct*16+(l&15)]
        const int wsel = (b - 625) >> 5;
        const float* W = wsel ? W2 : W1;
        short* Wswz = wsel ? w2s : w1s;
        const int idx = ((b - 625) & 31) * 256 + t;
        const int l = idx & 63, kt = (idx >> 6) & 3, ct = idx >> 8;
        const int k0 = kt * 32 + (l >> 4) * 8;
        const int col = ct * 16 + (l & 15);
        short v[8];
#pragma unroll
        for (int j = 0; j < 8; ++j) v[j] = (short)bf16_rne(W[(size_t)(k0 + j) * 512 + col]);
        *(bf16x8*)(Wswz + (size_t)idx * 8) = *(const bf16x8*)v;
    } else {
        const int e = (b - 689) * 256 + t;
        atomicAdd(&deg[dst[e]], 1);
    }
}

// ---------------- exclusive scan of deg -> rs, cursor
__global__ __launch_bounds__(1024) void exscan_kernel(const int* __restrict__ deg,
                                                      int* __restrict__ rs,
                                                      int* __restrict__ cursor) {
    __shared__ int part[1024];
    const int t = threadIdx.x;
    const int CH = 10;
    const int base = t * CH;
    int local[CH];
    int s = 0;
#pragma unroll
    for (int i = 0; i < CH; ++i) {
        int idx = base + i;
        int v = (idx < GN) ? deg[idx] : 0;
        local[i] = s;
        s += v;
    }
    part[t] = s;
    __syncthreads();
    for (int off = 1; off < 1024; off <<= 1) {
        int v = part[t];
        int u = (t >= off) ? part[t - off] : 0;
        __syncthreads();
        part[t] = v + u;
        __syncthreads();
    }
    const int chunk_base = (t == 0) ? 0 : part[t - 1];
#pragma unroll
    for (int i = 0; i < CH; ++i) {
        int idx = base + i;
        if (idx < GN) {
            int v = chunk_base + local[i];
            rs[idx] = v;
            cursor[idx] = v;
        }
    }
    if (t == 1023) rs[GN] = part[1023];
}

// ---------------- MFMA GEMM + fused logits (blocks 0..624) | CSR scatter (blocks 625..1249)
__global__ __launch_bounds__(256) void gemm_logits_scatter(
        const unsigned short* __restrict__ Xb, const short* __restrict__ Wswz,
        const float* __restrict__ al, const float* __restrict__ ar,
        unsigned short* __restrict__ Yb, float* __restrict__ el, float* __restrict__ er,
        const int* __restrict__ dst, const int* __restrict__ src,
        int* __restrict__ cursor, int* __restrict__ eidx, int* __restrict__ srcs) {
    if (blockIdx.x >= 625) {
        // scatter: CSR edge index AND CSR-ordered src
        const int e = (blockIdx.x - 625) * 256 + threadIdx.x;  // GE = 625*256
        const int sv = src[e];
        int p = atomicAdd(&cursor[dst[e]], 1);
        eidx[p] = e;
        srcs[p] = sv;
        return;
    }
    const int w = threadIdx.x >> 6, l = threadIdx.x & 63;
    const int row0 = blockIdx.x * 16;
    bf16x8 a[4];
    const unsigned short* xrow = Xb + (size_t)(row0 + (l & 15)) * 128 + (l >> 4) * 8;
#pragma unroll
    for (int kt = 0; kt < 4; ++kt) a[kt] = *(const bf16x8*)(xrow + kt * 32);
    float pel[4] = {0.f, 0.f, 0.f, 0.f}, per[4] = {0.f, 0.f, 0.f, 0.f};
#pragma unroll
    for (int c = 0; c < 8; ++c) {
        const int ct = w * 8 + c;
        f32x4 acc = {0.f, 0.f, 0.f, 0.f};
        const short* wp = Wswz + ((size_t)ct * 4 * 64 + l) * 8;
#pragma unroll
        for (int kt = 0; kt < 4; ++kt) {
            bf16x8 b = *(const bf16x8*)(wp + (size_t)kt * 64 * 8);
            acc = __builtin_amdgcn_mfma_f32_16x16x32_bf16(a[kt], b, acc, 0, 0, 0);
        }
        const int col = ct * 16 + (l & 15);
        const float alc = al[col], arc = ar[col];
        const int rbase = row0 + (l >> 4) * 4;
#pragma unroll
        for (int r = 0; r < 4; ++r) {
            const float v = acc[r];
            Yb[(size_t)(rbase + r) * 512 + col] = bf16_rne(v);
            pel[r] += v * alc;
            per[r] += v * arc;
        }
    }
#pragma unroll
    for (int r = 0; r < 4; ++r) {
#pragma unroll
        for (int off = 1; off < 16; off <<= 1) {
            pel[r] += __shfl_xor(pel[r], off);
            per[r] += __shfl_xor(per[r], off);
        }
    }
    if ((l & 15) == 0) {
        const int rbase = row0 + (l >> 4) * 4;
#pragma unroll
        for (int r = 0; r < 4; ++r) {
            el[(size_t)(rbase + r) * 4 + w] = pel[r];
            er[(size_t)(rbase + r) * 4 + w] = per[r];
        }
    }
}

// plain version for layer 2 (no scatter)
__global__ __launch_bounds__(256) void gemm_logits(const unsigned short* __restrict__ Xb,
                                                   const short* __restrict__ Wswz,
                                                   const float* __restrict__ al,
                                                   const float* __restrict__ ar,
                                                   unsigned short* __restrict__ Yb,
                                                   float* __restrict__ el,
                                                   float* __restrict__ er) {
    const int w = threadIdx.x >> 6, l = threadIdx.x & 63;
    const int row0 = blockIdx.x * 16;
    bf16x8 a[4];
    const unsigned short* xrow = Xb + (size_t)(row0 + (l & 15)) * 128 + (l >> 4) * 8;
#pragma unroll
    for (int kt = 0; kt < 4; ++kt) a[kt] = *(const bf16x8*)(xrow + kt * 32);
    float pel[4] = {0.f, 0.f, 0.f, 0.f}, per[4] = {0.f, 0.f, 0.f, 0.f};
#pragma unroll
    for (int c = 0; c < 8; ++c) {
        const int ct = w * 8 + c;
        f32x4 acc = {0.f, 0.f, 0.f, 0.f};
        const short* wp = Wswz + ((size_t)ct * 4 * 64 + l) * 8;
#pragma unroll
        for (int kt = 0; kt < 4; ++kt) {
            bf16x8 b = *(const bf16x8*)(wp + (size_t)kt * 64 * 8);
            acc = __builtin_amdgcn_mfma_f32_16x16x32_bf16(a[kt], b, acc, 0, 0, 0);
        }
        const int col = ct * 16 + (l & 15);
        const float alc = al[col], arc = ar[col];
        const int rbase = row0 + (l >> 4) * 4;
#pragma unroll
        for (int r = 0; r < 4; ++r) {
            const float v = acc[r];
            Yb[(size_t)(rbase + r) * 512 + col] = bf16_rne(v);
            pel[r] += v * alc;
            per[r] += v * arc;
        }
    }
#pragma unroll
    for (int r = 0; r < 4; ++r) {
#pragma unroll
        for (int off = 1; off < 16; off <<= 1) {
            pel[r] += __shfl_xor(pel[r], off);
            per[r] += __shfl_xor(per[r], off);
        }
    }
    if ((l & 15) == 0) {
        const int rbase = row0 + (l >> 4) * 4;
#pragma unroll
        for (int r = 0; r < 4; ++r) {
            el[(size_t)(rbase + r) * 4 + w] = pel[r];
            er[(size_t)(rbase + r) * 4 + w] = per[r];
        }
    }
}

__device__ __forceinline__ float head_sel(float a0, float a1, float a2, float a3, int lane) {
    float t01 = (lane & 16) ? a1 : a0;
    float t23 = (lane & 16) ? a3 : a2;
    return (lane & 32) ? t23 : t01;
}

__device__ __forceinline__ float4 eexp(float4 l, float4 e) {
    float4 o;
    o.x = __expf(leaky(l.x + e.x));
    o.y = __expf(leaky(l.y + e.y));
    o.z = __expf(leaky(l.z + e.z));
    o.w = __expf(leaky(l.w + e.w));
    return o;
}

__device__ __forceinline__ void acc_add(uint4 v, float aa, float* acc) {
    acc[0] += aa * bf_lo(v.x); acc[1] += aa * bf_hi(v.x);
    acc[2] += aa * bf_lo(v.y); acc[3] += aa * bf_hi(v.y);
    acc[4] += aa * bf_lo(v.z); acc[5] += aa * bf_hi(v.z);
    acc[6] += aa * bf_lo(v.w); acc[7] += aa * bf_hi(v.w);
}

// fused gather core: unroll-8 (8 rows in flight), in-loop exp, register denom
__device__ __forceinline__ void gcore_fused(int beg, int end,
                                            const int* __restrict__ srcs,
                                            const float4* __restrict__ el4, float4 ern,
                                            const unsigned short* __restrict__ hb,
                                            int lane, float* acc, float4& den) {
    int i = beg;
    for (; i + 7 < end; i += 8) {
        const int s0 = srcs[i],     s1 = srcs[i + 1], s2 = srcs[i + 2], s3 = srcs[i + 3];
        const int s4 = srcs[i + 4], s5 = srcs[i + 5], s6 = srcs[i + 6], s7 = srcs[i + 7];
        const float4 l0 = el4[s0], l1 = el4[s1], l2 = el4[s2], l3 = el4[s3];
        const float4 l4 = el4[s4], l5 = el4[s5], l6 = el4[s6], l7 = el4[s7];
        const uint4 r0 = ((const uint4*)(hb + (size_t)s0 * 512))[lane];
        const uint4 r1 = ((const uint4*)(hb + (size_t)s1 * 512))[lane];
        const uint4 r2 = ((const uint4*)(hb + (size_t)s2 * 512))[lane];
        const uint4 r3 = ((const uint4*)(hb + (size_t)s3 * 512))[lane];
        const uint4 r4 = ((const uint4*)(hb + (size_t)s4 * 512))[lane];
        const uint4 r5 = ((const uint4*)(hb + (size_t)s5 * 512))[lane];
        const uint4 r6 = ((const uint4*)(hb + (size_t)s6 * 512))[lane];
        const uint4 r7 = ((const uint4*)(hb + (size_t)s7 * 512))[lane];
        const float4 t0 = eexp(l0, ern), t1 = eexp(l1, ern), t2 = eexp(l2, ern), t3 = eexp(l3, ern);
        const float4 t4 = eexp(l4, ern), t5 = eexp(l5, ern), t6 = eexp(l6, ern), t7 = eexp(l7, ern);
        den.x += (t0.x + t1.x + t2.x + t3.x) + (t4.x + t5.x + t6.x + t7.x);
        den.y += (t0.y + t1.y + t2.y + t3.y) + (t4.y + t5.y + t6.y + t7.y);
        den.z += (t0.z + t1.z + t2.z + t3.z) + (t4.z + t5.z + t6.z + t7.z);
        den.w += (t0.w + t1.w + t2.w + t3.w) + (t4.w + t5.w + t6.w + t7.w);
        acc_add(r0, head_sel(t0.x, t0.y, t0.z, t0.w, lane), acc);
        acc_add(r1, head_sel(t1.x, t1.y, t1.z, t1.w, lane), acc);
        acc_add(r2, head_sel(t2.x, t2.y, t2.z, t2.w, lane), acc);
        acc_add(r3, head_sel(t3.x, t3.y, t3.z, t3.w, lane), acc);
        acc_add(r4, head_sel(t4.x, t4.y, t4.z, t4.w, lane), acc);
        acc_add(r5, head_sel(t5.x, t5.y, t5.z, t5.w, lane), acc);
        acc_add(r6, head_sel(t6.x, t6.y, t6.z, t6.w, lane), acc);
        acc_add(r7, head_sel(t7.x, t7.y, t7.z, t7.w, lane), acc);
    }
    for (; i + 3 < end; i += 4) {
        const int s0 = srcs[i], s1 = srcs[i + 1], s2 = srcs[i + 2], s3 = srcs[i + 3];
        const float4 l0 = el4[s0], l1 = el4[s1], l2 = el4[s2], l3 = el4[s3];
        const uint4 r0 = ((const uint4*)(hb + (size_t)s0 * 512))[lane];
        const uint4 r1 = ((const uint4*)(hb + (size_t)s1 * 512))[lane];
        const uint4 r2 = ((const uint4*)(hb + (size_t)s2 * 512))[lane];
        const uint4 r3 = ((const uint4*)(hb + (size_t)s3 * 512))[lane];
        const float4 t0 = eexp(l0, ern), t1 = eexp(l1, ern), t2 = eexp(l2, ern), t3 = eexp(l3, ern);
        den.x += t0.x + t1.x + t2.x + t3.x;
        den.y += t0.y + t1.y + t2.y + t3.y;
        den.z += t0.z + t1.z + t2.z + t3.z;
        den.w += t0.w + t1.w + t2.w + t3.w;
        acc_add(r0, head_sel(t0.x, t0.y, t0.z, t0.w, lane), acc);
        acc_add(r1, head_sel(t1.x, t1.y, t1.z, t1.w, lane), acc);
        acc_add(r2, head_sel(t2.x, t2.y, t2.z, t2.w, lane), acc);
        acc_add(r3, head_sel(t3.x, t3.y, t3.z, t3.w, lane), acc);
    }
    for (; i < end; ++i) {
        const int s0 = srcs[i];
        const float4 l0 = el4[s0];
        const uint4 r0 = ((const uint4*)(hb + (size_t)s0 * 512))[lane];
        const float4 t0 = eexp(l0, ern);
        den.x += t0.x; den.y += t0.y; den.z += t0.z; den.w += t0.w;
        acc_add(r0, head_sel(t0.x, t0.y, t0.z, t0.w, lane), acc);
    }
}

// ---------------- layer-1 gather: exp+denom+aggregate + bias + head-mean + LN + leaky -> h1b
__global__ __launch_bounds__(256) void gather_l1(const int* __restrict__ rs,
                                                 const int* __restrict__ srcs,
                                                 const unsigned short* __restrict__ hb,
                                                 const float* __restrict__ el,
                                                 const float* __restrict__ er,
                                                 const float* __restrict__ b1,
                                                 const float* __restrict__ ln_g,
                                                 const float* __restrict__ ln_b,
                                                 unsigned short* __restrict__ h1b) {
    const int wid = threadIdx.x >> 6, lane = threadIdx.x & 63;
    const int n = blockIdx.x * 4 + wid;  // GN % 4 == 0
    const int beg = rs[n], end = rs[n + 1];
    const float4 ern = ((const float4*)er)[n];
    float acc[8] = {0.f, 0.f, 0.f, 0.f, 0.f, 0.f, 0.f, 0.f};
    float4 den = {0.f, 0.f, 0.f, 0.f};
    gcore_fused(beg, end, srcs, (const float4*)el, ern, hb, lane, acc, den);
    const float invh = head_sel(1.f / fmaxf(den.x, 1e-9f), 1.f / fmaxf(den.y, 1e-9f),
                                1.f / fmaxf(den.z, 1e-9f), 1.f / fmaxf(den.w, 1e-9f), lane);
    float m[8];
#pragma unroll
    for (int j = 0; j < 8; ++j) m[j] = acc[j] * invh + b1[8 * lane + j];
#pragma unroll
    for (int j = 0; j < 8; ++j) {
        m[j] += __shfl_xor(m[j], 16);
        m[j] += __shfl_xor(m[j], 32);
        m[j] *= 0.25f;
    }
    float s = 0.f;
#pragma unroll
    for (int j = 0; j < 8; ++j) s += m[j];
#pragma unroll
    for (int off = 32; off; off >>= 1) s += __shfl_xor(s, off);
    const float mean = s * (1.0f / 512.0f);
    float q = 0.f;
#pragma unroll
    for (int j = 0; j < 8; ++j) { float d = m[j] - mean; q += d * d; }
#pragma unroll
    for (int off = 32; off; off >>= 1) q += __shfl_xor(q, off);
    const float inv = rsqrtf(q * (1.0f / 512.0f) + 1e-5f);
    if (lane < 16) {
        const int d0 = 8 * lane;
        ushort o[8];
#pragma unroll
        for (int j = 0; j < 8; ++j)
            o[j] = bf16_rne(leaky((m[j] - mean) * inv * ln_g[d0 + j] + ln_b[d0 + j]));
        ((uint4*)(h1b + (size_t)n * 128 + d0))[0] = *(const uint4*)o;
    }
}

// ---------------- layer-2 gather: exp+denom+aggregate + aw + bias + leaky + pooled max
__global__ __launch_bounds__(256) void gather_l2(const int* __restrict__ rs,
                                                 const int* __restrict__ srcs,
                                                 const int* __restrict__ eidx,
                                                 const unsigned short* __restrict__ hb,
                                                 const float* __restrict__ el,
                                                 const float* __restrict__ er,
                                                 const float* __restrict__ b2,
                                                 const int* __restrict__ gid,
                                                 unsigned* __restrict__ pooled,
                                                 float* __restrict__ aw) {
    __shared__ unsigned pool_s[4][512];
    __shared__ int gids[4];
    const int wid = threadIdx.x >> 6, lane = threadIdx.x & 63;
    const int n = blockIdx.x * 4 + wid;  // GN % 4 == 0
    const int beg = rs[n], end = rs[n + 1];
    const float4 ern = ((const float4*)er)[n];
    const float4* el4 = (const float4*)el;
    float acc[8] = {0.f, 0.f, 0.f, 0.f, 0.f, 0.f, 0.f, 0.f};
    float4 den = {0.f, 0.f, 0.f, 0.f};
    gcore_fused(beg, end, srcs, el4, ern, hb, lane, acc, den);
    const float i0 = 1.f / fmaxf(den.x, 1e-9f), i1 = 1.f / fmaxf(den.y, 1e-9f);
    const float i2 = 1.f / fmaxf(den.z, 1e-9f), i3 = 1.f / fmaxf(den.w, 1e-9f);
    // aw: lane-distributed recompute (identical exp -> identical values)
    for (int i = beg + lane; i < end; i += 64) {
        const float4 l = el4[srcs[i]];
        const float4 t = eexp(l, ern);
        ((float4*)aw)[eidx[i]] = make_float4(t.x * i0, t.y * i1, t.z * i2, t.w * i3);
    }
    const float invh = head_sel(i0, i1, i2, i3, lane);
    const int f0 = 8 * lane;
    unsigned k[8];
#pragma unroll
    for (int j = 0; j < 8; ++j) {
        const float v = leaky(acc[j] * invh + b2[f0 + j]);
        unsigned bits = __float_as_uint(v);
        k[j] = (bits & 0x80000000u) ? ~bits : (bits | 0x80000000u);
    }
    uint4* row = (uint4*)&pool_s[wid][f0];
    row[0] = make_uint4(k[0], k[1], k[2], k[3]);
    row[1] = make_uint4(k[4], k[5], k[6], k[7]);
    if (lane == 0) gids[wid] = gid[n];
    __syncthreads();
    const int g0 = gids[0];
    if ((gids[1] == g0) & (gids[2] == g0) & (gids[3] == g0)) {
        unsigned* pg = pooled + (size_t)g0 * 512;
        const int t = threadIdx.x;
#pragma unroll
        for (int rep = 0; rep < 2; ++rep) {
            const int f = t + rep * 256;
            unsigned kk = max(max(pool_s[0][f], pool_s[1][f]),
                              max(pool_s[2][f], pool_s[3][f]));
            atomicMax(&pg[f], kk);
        }
    } else {
        unsigned* pg = pooled + (size_t)gids[wid] * 512;
#pragma unroll
        for (int j = 0; j < 8; ++j) {
            const int f = lane + 64 * j;
            atomicMax(&pg[f], pool_s[wid][f]);
        }
    }
}

__device__ __forceinline__ float blk_sum(float v, float* red) {
#pragma unroll
    for (int off = 32; off; off >>= 1) v += __shfl_xor(v, off);
    const int wid = threadIdx.x >> 6, lane = threadIdx.x & 63;
    __syncthreads();
    if (lane == 0) red[wid] = v;
    __syncthreads();
    return red[0] + red[1] + red[2] + red[3];
}

// ---------------- head MLP: one block per graph, ILP-pipelined matvecs
__global__ __launch_bounds__(256) void head_mlp(const unsigned* __restrict__ pooled,
                                                const float* __restrict__ Wa, const float* __restrict__ ba,
                                                const float* __restrict__ Wb, const float* __restrict__ bb,
                                                const float* __restrict__ g2, const float* __restrict__ bt2,
                                                const float* __restrict__ Wc, const float* __restrict__ bc,
                                                float* __restrict__ probs) {
    __shared__ float p[512];
    __shared__ float z1h[2][128];
    __shared__ float z1[128];
    __shared__ float z2[768];
    __shared__ float red[4];
    const int g = blockIdx.x, t = threadIdx.x;
    for (int i = t; i < 512; i += 256) {
        unsigned key = pooled[(size_t)g * 512 + i];
        unsigned bits = (key & 0x80000000u) ? (key ^ 0x80000000u) : ~key;
        p[i] = __uint_as_float(bits);
    }
    __syncthreads();
    {
        const int j = t & 127;
        const int c0 = (t >> 7) * 256;
        float a0 = 0.f, a1 = 0.f, a2 = 0.f, a3 = 0.f;
#pragma unroll 8
        for (int c = 0; c < 256; c += 4) {
            a0 += p[c0 + c]     * Wa[(size_t)(c0 + c) * 128 + j];
            a1 += p[c0 + c + 1] * Wa[(size_t)(c0 + c + 1) * 128 + j];
            a2 += p[c0 + c + 2] * Wa[(size_t)(c0 + c + 2) * 128 + j];
            a3 += p[c0 + c + 3] * Wa[(size_t)(c0 + c + 3) * 128 + j];
        }
        z1h[t >> 7][j] = (a0 + a1) + (a2 + a3);
    }
    __syncthreads();
    if (t < 128) z1[t] = z1h[0][t] + z1h[1][t] + ba[t];
    __syncthreads();
    {
        float a00 = 0.f, a01 = 0.f, a10 = 0.f, a11 = 0.f, a20 = 0.f, a21 = 0.f;
#pragma unroll 8
        for (int j = 0; j < 64; ++j) {
            const float p0 = z1[j], p1 = z1[j + 64];
            a00 += p0 * Wb[(size_t)j * 768 + t];
            a01 += p1 * Wb[(size_t)(j + 64) * 768 + t];
            a10 += p0 * Wb[(size_t)j * 768 + t + 256];
            a11 += p1 * Wb[(size_t)(j + 64) * 768 + t + 256];
            a20 += p0 * Wb[(size_t)j * 768 + t + 512];
            a21 += p1 * Wb[(size_t)(j + 64) * 768 + t + 512];
        }
        z2[t]       = a00 + a01 + bb[t];
        z2[t + 256] = a10 + a11 + bb[t + 256];
        z2[t + 512] = a20 + a21 + bb[t + 512];
    }
    __syncthreads();
    float s = 0.f;
    for (int k = t; k < 768; k += 256) s += z2[k];
    const float mean = blk_sum(s, red) * (1.0f / 768.0f);
    float q = 0.f;
    for (int k = t; k < 768; k += 256) { float d = z2[k] - mean; q += d * d; }
    const float inv = rsqrtf(blk_sum(q, red) * (1.0f / 768.0f) + 1e-5f);
    __syncthreads();
    for (int k = t; k < 768; k += 256)
        z2[k] = leaky((z2[k] - mean) * inv * g2[k] + bt2[k]);
    __syncthreads();
    float a0 = 0.f, a1 = 0.f;
    for (int k = t; k < 768; k += 256) { a0 += z2[k] * Wc[k * 2]; a1 += z2[k] * Wc[k * 2 + 1]; }
    a0 = blk_sum(a0, red);
    a1 = blk_sum(a1, red);
    if (t == 0) {
        a0 += bc[0]; a1 += bc[1];
        const float m = fmaxf(a0, a1);
        const float e0 = __expf(a0 - m), e1 = __expf(a1 - m);
        const float den = e0 + e1;
        probs[g * 2 + 0] = e0 / den;
        probs[g * 2 + 1] = e1 / den;
    }
}

extern "C" void kernel_launch(void* const* d_in, const int* in_sizes, int n_in,
                              void* d_out, int out_size, void* d_ws, size_t ws_size,
                              hipStream_t stream) {
    const float* x   = (const float*)d_in[0];
    const int* src   = (const int*)d_in[1];
    const int* dst   = (const int*)d_in[2];
    const int* gid   = (const int*)d_in[3];
    const float* W1  = (const float*)d_in[4];
    const float* al1 = (const float*)d_in[5];
    const float* ar1 = (const float*)d_in[6];
    const float* b1  = (const float*)d_in[7];
    const float* lng = (const float*)d_in[8];
    const float* lnb = (const float*)d_in[9];
    const float* W2  = (const float*)d_in[10];
    const float* al2 = (const float*)d_in[11];
    const float* ar2 = (const float*)d_in[12];
    const float* b2  = (const float*)d_in[13];
    const float* Wa  = (const float*)d_in[14];
    const float* ba  = (const float*)d_in[15];
    const float* Wb  = (const float*)d_in[16];
    const float* bb  = (const float*)d_in[17];
    const float* g2  = (const float*)d_in[18];
    const float* bt2 = (const float*)d_in[19];
    const float* Wc  = (const float*)d_in[20];
    const float* bc  = (const float*)d_in[21];

    char* ws = (char*)d_ws;
    unsigned short* hb  = (unsigned short*)ws;                    // N*512 bf16
    unsigned short* xb  = hb + (size_t)GN * 512;                  // N*128 bf16
    unsigned short* h1b = xb + (size_t)GN * 128;                  // N*128 bf16
    short* w1s = (short*)(h1b + (size_t)GN * 128);                // 8192*8 bf16
    short* w2s = w1s + 8192 * 8;                                  // 8192*8 bf16
    float* el    = (float*)(w2s + 8192 * 8);                      // N*4
    float* er    = el + GN * 4;                                   // N*4
    int* eidx    = (int*)(er + GN * 4);                           // E
    int* srcs    = eidx + GE;                                     // E (CSR-ordered src)
    int* cursor  = srcs + GE;                                     // N
    // ---- contiguous zero region (single memset): deg | pooled
    int* deg       = cursor + GN;                                 // N
    unsigned* pooled = (unsigned*)(deg + GN);                     // B*512
    const size_t zero_bytes = (size_t)GN * 4 + (size_t)GB * 512 * 4;
    int* rs = (int*)(pooled + GB * 512);                          // N+1

    float* probs = (float*)d_out;
    float* aw = probs + GB * GC;  // E*4 floats

    hipMemsetAsync(deg, 0, zero_bytes, stream);
    prep_misc<<<1314, 256, 0, stream>>>(x, xb, W1, w1s, W2, w2s, dst, deg);
    exscan_kernel<<<1, 1024, 0, stream>>>(deg, rs, cursor);

    // ---- layer 1 GEMM + CSR scatter in one launch
    gemm_logits_scatter<<<1250, 256, 0, stream>>>(xb, w1s, al1, ar1, hb, el, er,
                                                  dst, src, cursor, eidx, srcs);
    gather_l1<<<GN / 4, 256, 0, stream>>>(rs, srcs, hb, el, er, b1, lng, lnb, h1b);

    // ---- layer 2
    gemm_logits<<<GN / 16, 256, 0, stream>>>(h1b, w2s, al2, ar2, hb, el, er);
    gather_l2<<<GN / 4, 256, 0, stream>>>(rs, srcs, eidx, hb, el, er, b2, gid, pooled, aw);

    // ---- head
    head_mlp<<<GB, 256, 0, stream>>>(pooled, Wa, ba, Wb, bb, g2, bt2, Wc, bc, probs);
}

// Round 10
// 143.254 us; speedup vs baseline: 1.0275x; 1.0275x over previous
//
#include <hip/hip_runtime.h>
#include <hip/hip_bf16.h>

#define GN 10000
#define GE 160000
#define GH 4
#define GD 128
#define GHD 512
#define GB 64
#define GC 2
#define GFF 768
#define SLOPE 0.2f

typedef __attribute__((ext_vector_type(8))) short bf16x8;
typedef __attribute__((ext_vector_type(4))) float f32x4;

__device__ __forceinline__ float leaky(float x) { return x >= 0.0f ? x : SLOPE * x; }

__device__ __forceinline__ unsigned short bf16_rne(float f) {
    unsigned u = __float_as_uint(f);
    u += 0x7fffu + ((u >> 16) & 1u);
    return (unsigned short)(u >> 16);
}
__device__ __forceinline__ float bf_lo(unsigned u) { return __uint_as_float(u << 16); }
__device__ __forceinline__ float bf_hi(unsigned u) { return __uint_as_float(u & 0xffff0000u); }

// ---------------- fused prep: conv_bf16 (625 blocks) | prep_w1 (32) | prep_w2 (32) | hist (625)
__global__ __launch_bounds__(256) void prep_misc(const float* __restrict__ x,
                                                 unsigned short* __restrict__ xb,
                                                 const float* __restrict__ W1,
                                                 short* __restrict__ w1s,
                                                 const float* __restrict__ W2,
                                                 short* __restrict__ w2s,
                                                 const int* __restrict__ dst,
                                                 int* __restrict__ deg) {
    const int b = blockIdx.x, t = threadIdx.x;
    if (b < 625) {
        const int i = b * 256 + t;
        const float4 a = ((const float4*)x)[i * 2];
        const float4 c = ((const float4*)x)[i * 2 + 1];
        ushort o[8] = {bf16_rne(a.x), bf16_rne(a.y), bf16_rne(a.z), bf16_rne(a.w),
                       bf16_rne(c.x), bf16_rne(c.y), bf16_rne(c.z), bf16_rne(c.w)};
        ((uint4*)xb)[i] = *(const uint4*)o;
    } else if (b < 689) {
        // W [128,512] f32 -> B-fragment bf16: [ct(32)][kt(4)][lane(64)][8]
        // lane l, reg j -> B[k=kt*32+(l>>4)*8+j][col=ct*16+(l&15)]
        const int wsel = (b - 625) >> 5;
        const float* W = wsel ? W2 : W1;
        short* Wswz = wsel ? w2s : w1s;
        const int idx = ((b - 625) & 31) * 256 + t;
        const int l = idx & 63, kt = (idx >> 6) & 3, ct = idx >> 8;
        const int k0 = kt * 32 + (l >> 4) * 8;
        const int col = ct * 16 + (l & 15);
        short v[8];
#pragma unroll
        for (int j = 0; j < 8; ++j) v[j] = (short)bf16_rne(W[(size_t)(k0 + j) * 512 + col]);
        *(bf16x8*)(Wswz + (size_t)idx * 8) = *(const bf16x8*)v;
    } else {
        const int e = (b - 689) * 256 + t;
        atomicAdd(&deg[dst[e]], 1);
    }
}

// ---------------- exclusive scan of deg -> rs, cursor
__global__ __launch_bounds__(1024) void exscan_kernel(const int* __restrict__ deg,
                                                      int* __restrict__ rs,
                                                      int* __restrict__ cursor) {
    __shared__ int part[1024];
    const int t = threadIdx.x;
    const int CH = 10;
    const int base = t * CH;
    int local[CH];
    int s = 0;
#pragma unroll
    for (int i = 0; i < CH; ++i) {
        int idx = base + i;
        int v = (idx < GN) ? deg[idx] : 0;
        local[i] = s;
        s += v;
    }
    part[t] = s;
    __syncthreads();
    for (int off = 1; off < 1024; off <<= 1) {
        int v = part[t];
        int u = (t >= off) ? part[t - off] : 0;
        __syncthreads();
        part[t] = v + u;
        __syncthreads();
    }
    const int chunk_base = (t == 0) ? 0 : part[t - 1];
#pragma unroll
    for (int i = 0; i < CH; ++i) {
        int idx = base + i;
        if (idx < GN) {
            int v = chunk_base + local[i];
            rs[idx] = v;
            cursor[idx] = v;
        }
    }
    if (t == 1023) rs[GN] = part[1023];
}

// scatter: CSR edge index AND CSR-ordered src (kills one gather indirection)
__global__ __launch_bounds__(256) void scatter_kernel(const int* __restrict__ dst,
                                                      const int* __restrict__ src,
                                                      int* __restrict__ cursor,
                                                      int* __restrict__ eidx,
                                                      int* __restrict__ srcs) {
    const int e = blockIdx.x * blockDim.x + threadIdx.x;  // GE = 625*256 exact
    const int sv = src[e];
    int p = atomicAdd(&cursor[dst[e]], 1);
    eidx[p] = e;
    srcs[p] = sv;
}

// ---------------- MFMA GEMM + fused attention logits (wave w == head w)
__global__ __launch_bounds__(256) void gemm_logits(const unsigned short* __restrict__ Xb,
                                                   const short* __restrict__ Wswz,
                                                   const float* __restrict__ al,
                                                   const float* __restrict__ ar,
                                                   unsigned short* __restrict__ Yb,
                                                   float* __restrict__ el,
                                                   float* __restrict__ er) {
    const int w = threadIdx.x >> 6, l = threadIdx.x & 63;
    const int row0 = blockIdx.x * 16;
    bf16x8 a[4];
    const unsigned short* xrow = Xb + (size_t)(row0 + (l & 15)) * 128 + (l >> 4) * 8;
#pragma unroll
    for (int kt = 0; kt < 4; ++kt) a[kt] = *(const bf16x8*)(xrow + kt * 32);
    float pel[4] = {0.f, 0.f, 0.f, 0.f}, per[4] = {0.f, 0.f, 0.f, 0.f};
#pragma unroll
    for (int c = 0; c < 8; ++c) {
        const int ct = w * 8 + c;
        f32x4 acc = {0.f, 0.f, 0.f, 0.f};
        const short* wp = Wswz + ((size_t)ct * 4 * 64 + l) * 8;
#pragma unroll
        for (int kt = 0; kt < 4; ++kt) {
            bf16x8 b = *(const bf16x8*)(wp + (size_t)kt * 64 * 8);
            acc = __builtin_amdgcn_mfma_f32_16x16x32_bf16(a[kt], b, acc, 0, 0, 0);
        }
        const int col = ct * 16 + (l & 15);
        const float alc = al[col], arc = ar[col];
        const int rbase = row0 + (l >> 4) * 4;
#pragma unroll
        for (int r = 0; r < 4; ++r) {
            const float v = acc[r];
            Yb[(size_t)(rbase + r) * 512 + col] = bf16_rne(v);
            pel[r] += v * alc;
            per[r] += v * arc;
        }
    }
#pragma unroll
    for (int r = 0; r < 4; ++r) {
#pragma unroll
        for (int off = 1; off < 16; off <<= 1) {
            pel[r] += __shfl_xor(pel[r], off);
            per[r] += __shfl_xor(per[r], off);
        }
    }
    if ((l & 15) == 0) {
        const int rbase = row0 + (l >> 4) * 4;
#pragma unroll
        for (int r = 0; r < 4; ++r) {
            el[(size_t)(rbase + r) * 4 + w] = pel[r];
            er[(size_t)(rbase + r) * 4 + w] = per[r];
        }
    }
}

__device__ __forceinline__ float head_sel(float a0, float a1, float a2, float a3, int lane) {
    float t01 = (lane & 16) ? a1 : a0;
    float t23 = (lane & 16) ? a3 : a2;
    return (lane & 32) ? t23 : t01;
}

__device__ __forceinline__ float4 eexp(float4 l, float4 e) {
    float4 o;
    o.x = __expf(leaky(l.x + e.x));
    o.y = __expf(leaky(l.y + e.y));
    o.z = __expf(leaky(l.z + e.z));
    o.w = __expf(leaky(l.w + e.w));
    return o;
}

__device__ __forceinline__ void acc_add(uint4 v, float aa, float* acc) {
    acc[0] += aa * bf_lo(v.x); acc[1] += aa * bf_hi(v.x);
    acc[2] += aa * bf_lo(v.y); acc[3] += aa * bf_hi(v.y);
    acc[4] += aa * bf_lo(v.z); acc[5] += aa * bf_hi(v.z);
    acc[6] += aa * bf_lo(v.w); acc[7] += aa * bf_hi(v.w);
}

// fused gather core: CSR-ordered srcs (1 indirection), in-loop exp, register denom (unroll 4)
__device__ __forceinline__ void gcore_fused(int beg, int end,
                                            const int* __restrict__ srcs,
                                            const float4* __restrict__ el4, float4 ern,
                                            const unsigned short* __restrict__ hb,
                                            int lane, float* acc, float4& den) {
    int i = beg;
    for (; i + 3 < end; i += 4) {
        const int s0 = srcs[i], s1 = srcs[i + 1], s2 = srcs[i + 2], s3 = srcs[i + 3];
        const float4 l0 = el4[s0], l1 = el4[s1], l2 = el4[s2], l3 = el4[s3];
        const uint4 r0 = ((const uint4*)(hb + (size_t)s0 * 512))[lane];
        const uint4 r1 = ((const uint4*)(hb + (size_t)s1 * 512))[lane];
        const uint4 r2 = ((const uint4*)(hb + (size_t)s2 * 512))[lane];
        const uint4 r3 = ((const uint4*)(hb + (size_t)s3 * 512))[lane];
        const float4 t0 = eexp(l0, ern), t1 = eexp(l1, ern), t2 = eexp(l2, ern), t3 = eexp(l3, ern);
        den.x += t0.x + t1.x + t2.x + t3.x;
        den.y += t0.y + t1.y + t2.y + t3.y;
        den.z += t0.z + t1.z + t2.z + t3.z;
        den.w += t0.w + t1.w + t2.w + t3.w;
        acc_add(r0, head_sel(t0.x, t0.y, t0.z, t0.w, lane), acc);
        acc_add(r1, head_sel(t1.x, t1.y, t1.z, t1.w, lane), acc);
        acc_add(r2, head_sel(t2.x, t2.y, t2.z, t2.w, lane), acc);
        acc_add(r3, head_sel(t3.x, t3.y, t3.z, t3.w, lane), acc);
    }
    for (; i < end; ++i) {
        const int s0 = srcs[i];
        const float4 l0 = el4[s0];
        const uint4 r0 = ((const uint4*)(hb + (size_t)s0 * 512))[lane];
        const float4 t0 = eexp(l0, ern);
        den.x += t0.x; den.y += t0.y; den.z += t0.z; den.w += t0.w;
        acc_add(r0, head_sel(t0.x, t0.y, t0.z, t0.w, lane), acc);
    }
}

// ---------------- layer-1 gather: exp+denom+aggregate + bias + head-mean + LN + leaky -> h1b
__global__ __launch_bounds__(256) void gather_l1(const int* __restrict__ rs,
                                                 const int* __restrict__ srcs,
                                                 const unsigned short* __restrict__ hb,
                                                 const float* __restrict__ el,
                                                 const float* __restrict__ er,
                                                 const float* __restrict__ b1,
                                                 const float* __restrict__ ln_g,
                                                 const float* __restrict__ ln_b,
                                                 unsigned short* __restrict__ h1b) {
    const int wid = threadIdx.x >> 6, lane = threadIdx.x & 63;
    const int n = blockIdx.x * 4 + wid;  // GN % 4 == 0
    const int beg = rs[n], end = rs[n + 1];
    const float4 ern = ((const float4*)er)[n];
    float acc[8] = {0.f, 0.f, 0.f, 0.f, 0.f, 0.f, 0.f, 0.f};
    float4 den = {0.f, 0.f, 0.f, 0.f};
    gcore_fused(beg, end, srcs, (const float4*)el, ern, hb, lane, acc, den);
    const float invh = head_sel(1.f / fmaxf(den.x, 1e-9f), 1.f / fmaxf(den.y, 1e-9f),
                                1.f / fmaxf(den.z, 1e-9f), 1.f / fmaxf(den.w, 1e-9f), lane);
    float m[8];
#pragma unroll
    for (int j = 0; j < 8; ++j) m[j] = acc[j] * invh + b1[8 * lane + j];
#pragma unroll
    for (int j = 0; j < 8; ++j) {
        m[j] += __shfl_xor(m[j], 16);
        m[j] += __shfl_xor(m[j], 32);
        m[j] *= 0.25f;
    }
    float s = 0.f;
#pragma unroll
    for (int j = 0; j < 8; ++j) s += m[j];
#pragma unroll
    for (int off = 32; off; off >>= 1) s += __shfl_xor(s, off);
    const float mean = s * (1.0f / 512.0f);
    float q = 0.f;
#pragma unroll
    for (int j = 0; j < 8; ++j) { float d = m[j] - mean; q += d * d; }
#pragma unroll
    for (int off = 32; off; off >>= 1) q += __shfl_xor(q, off);
    const float inv = rsqrtf(q * (1.0f / 512.0f) + 1e-5f);
    if (lane < 16) {
        const int d0 = 8 * lane;
        ushort o[8];
#pragma unroll
        for (int j = 0; j < 8; ++j)
            o[j] = bf16_rne(leaky((m[j] - mean) * inv * ln_g[d0 + j] + ln_b[d0 + j]));
        ((uint4*)(h1b + (size_t)n * 128 + d0))[0] = *(const uint4*)o;
    }
}

// ---------------- layer-2 gather: exp+denom+aggregate + aw + bias + leaky + pooled max
__global__ __launch_bounds__(256) void gather_l2(const int* __restrict__ rs,
                                                 const int* __restrict__ srcs,
                                                 const int* __restrict__ eidx,
                                                 const unsigned short* __restrict__ hb,
                                                 const float* __restrict__ el,
                                                 const float* __restrict__ er,
                                                 const float* __restrict__ b2,
                                                 const int* __restrict__ gid,
                                                 unsigned* __restrict__ pooled,
                                                 float* __restrict__ aw) {
    __shared__ unsigned pool_s[4][512];
    __shared__ int gids[4];
    const int wid = threadIdx.x >> 6, lane = threadIdx.x & 63;
    const int n = blockIdx.x * 4 + wid;  // GN % 4 == 0
    const int beg = rs[n], end = rs[n + 1];
    const float4 ern = ((const float4*)er)[n];
    const float4* el4 = (const float4*)el;
    float acc[8] = {0.f, 0.f, 0.f, 0.f, 0.f, 0.f, 0.f, 0.f};
    float4 den = {0.f, 0.f, 0.f, 0.f};
    gcore_fused(beg, end, srcs, el4, ern, hb, lane, acc, den);
    const float i0 = 1.f / fmaxf(den.x, 1e-9f), i1 = 1.f / fmaxf(den.y, 1e-9f);
    const float i2 = 1.f / fmaxf(den.z, 1e-9f), i3 = 1.f / fmaxf(den.w, 1e-9f);
    // aw: lane-distributed recompute (identical exp -> identical values)
    for (int i = beg + lane; i < end; i += 64) {
        const float4 l = el4[srcs[i]];
        const float4 t = eexp(l, ern);
        ((float4*)aw)[eidx[i]] = make_float4(t.x * i0, t.y * i1, t.z * i2, t.w * i3);
    }
    const float invh = head_sel(i0, i1, i2, i3, lane);
    const int f0 = 8 * lane;
    unsigned k[8];
#pragma unroll
    for (int j = 0; j < 8; ++j) {
        const float v = leaky(acc[j] * invh + b2[f0 + j]);
        unsigned bits = __float_as_uint(v);
        k[j] = (bits & 0x80000000u) ? ~bits : (bits | 0x80000000u);
    }
    uint4* row = (uint4*)&pool_s[wid][f0];
    row[0] = make_uint4(k[0], k[1], k[2], k[3]);
    row[1] = make_uint4(k[4], k[5], k[6], k[7]);
    if (lane == 0) gids[wid] = gid[n];
    __syncthreads();
    const int g0 = gids[0];
    if ((gids[1] == g0) & (gids[2] == g0) & (gids[3] == g0)) {
        unsigned* pg = pooled + (size_t)g0 * 512;
        const int t = threadIdx.x;
#pragma unroll
        for (int rep = 0; rep < 2; ++rep) {
            const int f = t + rep * 256;
            unsigned kk = max(max(pool_s[0][f], pool_s[1][f]),
                              max(pool_s[2][f], pool_s[3][f]));
            atomicMax(&pg[f], kk);
        }
    } else {
        unsigned* pg = pooled + (size_t)gids[wid] * 512;
#pragma unroll
        for (int j = 0; j < 8; ++j) {
            const int f = lane + 64 * j;
            atomicMax(&pg[f], pool_s[wid][f]);
        }
    }
}

__device__ __forceinline__ float blk_sum(float v, float* red) {
#pragma unroll
    for (int off = 32; off; off >>= 1) v += __shfl_xor(v, off);
    const int wid = threadIdx.x >> 6, lane = threadIdx.x & 63;
    __syncthreads();
    if (lane == 0) red[wid] = v;
    __syncthreads();
    return red[0] + red[1] + red[2] + red[3];
}

// ---------------- head MLP: one block per graph, ILP-pipelined matvecs
__global__ __launch_bounds__(256) void head_mlp(const unsigned* __restrict__ pooled,
                                                const float* __restrict__ Wa, const float* __restrict__ ba,
                                                const float* __restrict__ Wb, const float* __restrict__ bb,
                                                const float* __restrict__ g2, const float* __restrict__ bt2,
                                                const float* __restrict__ Wc, const float* __restrict__ bc,
                                                float* __restrict__ probs) {
    __shared__ float p[512];
    __shared__ float z1h[2][128];
    __shared__ float z1[128];
    __shared__ float z2[768];
    __shared__ float red[4];
    const int g = blockIdx.x, t = threadIdx.x;
    for (int i = t; i < 512; i += 256) {
        unsigned key = pooled[(size_t)g * 512 + i];
        unsigned bits = (key & 0x80000000u) ? (key ^ 0x80000000u) : ~key;
        p[i] = __uint_as_float(bits);
    }
    __syncthreads();
    {
        const int j = t & 127;
        const int c0 = (t >> 7) * 256;
        float a0 = 0.f, a1 = 0.f, a2 = 0.f, a3 = 0.f;
#pragma unroll 8
        for (int c = 0; c < 256; c += 4) {
            a0 += p[c0 + c]     * Wa[(size_t)(c0 + c) * 128 + j];
            a1 += p[c0 + c + 1] * Wa[(size_t)(c0 + c + 1) * 128 + j];
            a2 += p[c0 + c + 2] * Wa[(size_t)(c0 + c + 2) * 128 + j];
            a3 += p[c0 + c + 3] * Wa[(size_t)(c0 + c + 3) * 128 + j];
        }
        z1h[t >> 7][j] = (a0 + a1) + (a2 + a3);
    }
    __syncthreads();
    if (t < 128) z1[t] = z1h[0][t] + z1h[1][t] + ba[t];
    __syncthreads();
    {
        float a00 = 0.f, a01 = 0.f, a10 = 0.f, a11 = 0.f, a20 = 0.f, a21 = 0.f;
#pragma unroll 8
        for (int j = 0; j < 64; ++j) {
            const float p0 = z1[j], p1 = z1[j + 64];
            a00 += p0 * Wb[(size_t)j * 768 + t];
            a01 += p1 * Wb[(size_t)(j + 64) * 768 + t];
            a10 += p0 * Wb[(size_t)j * 768 + t + 256];
            a11 += p1 * Wb[(size_t)(j + 64) * 768 + t + 256];
            a20 += p0 * Wb[(size_t)j * 768 + t + 512];
            a21 += p1 * Wb[(size_t)(j + 64) * 768 + t + 512];
        }
        z2[t]       = a00 + a01 + bb[t];
        z2[t + 256] = a10 + a11 + bb[t + 256];
        z2[t + 512] = a20 + a21 + bb[t + 512];
    }
    __syncthreads();
    float s = 0.f;
    for (int k = t; k < 768; k += 256) s += z2[k];
    const float mean = blk_sum(s, red) * (1.0f / 768.0f);
    float q = 0.f;
    for (int k = t; k < 768; k += 256) { float d = z2[k] - mean; q += d * d; }
    const float inv = rsqrtf(blk_sum(q, red) * (1.0f / 768.0f) + 1e-5f);
    __syncthreads();
    for (int k = t; k < 768; k += 256)
        z2[k] = leaky((z2[k] - mean) * inv * g2[k] + bt2[k]);
    __syncthreads();
    float a0 = 0.f, a1 = 0.f;
    for (int k = t; k < 768; k += 256) { a0 += z2[k] * Wc[k * 2]; a1 += z2[k] * Wc[k * 2 + 1]; }
    a0 = blk_sum(a0, red);
    a1 = blk_sum(a1, red);
    if (t == 0) {
        a0 += bc[0]; a1 += bc[1];
        const float m = fmaxf(a0, a1);
        const float e0 = __expf(a0 - m), e1 = __expf(a1 - m);
        const float den = e0 + e1;
        probs[g * 2 + 0] = e0 / den;
        probs[g * 2 + 1] = e1 / den;
    }
}

extern "C" void kernel_launch(void* const* d_in, const int* in_sizes, int n_in,
                              void* d_out, int out_size, void* d_ws, size_t ws_size,
                              hipStream_t stream) {
    const float* x   = (const float*)d_in[0];
    const int* src   = (const int*)d_in[1];
    const int* dst   = (const int*)d_in[2];
    const int* gid   = (const int*)d_in[3];
    const float* W1  = (const float*)d_in[4];
    const float* al1 = (const float*)d_in[5];
    const float* ar1 = (const float*)d_in[6];
    const float* b1  = (const float*)d_in[7];
    const float* lng = (const float*)d_in[8];
    const float* lnb = (const float*)d_in[9];
    const float* W2  = (const float*)d_in[10];
    const float* al2 = (const float*)d_in[11];
    const float* ar2 = (const float*)d_in[12];
    const float* b2  = (const float*)d_in[13];
    const float* Wa  = (const float*)d_in[14];
    const float* ba  = (const float*)d_in[15];
    const float* Wb  = (const float*)d_in[16];
    const float* bb  = (const float*)d_in[17];
    const float* g2  = (const float*)d_in[18];
    const float* bt2 = (const float*)d_in[19];
    const float* Wc  = (const float*)d_in[20];
    const float* bc  = (const float*)d_in[21];

    char* ws = (char*)d_ws;
    unsigned short* hb  = (unsigned short*)ws;                    // N*512 bf16
    unsigned short* xb  = hb + (size_t)GN * 512;                  // N*128 bf16
    unsigned short* h1b = xb + (size_t)GN * 128;                  // N*128 bf16
    short* w1s = (short*)(h1b + (size_t)GN * 128);                // 8192*8 bf16
    short* w2s = w1s + 8192 * 8;                                  // 8192*8 bf16
    float* el    = (float*)(w2s + 8192 * 8);                      // N*4
    float* er    = el + GN * 4;                                   // N*4
    int* eidx    = (int*)(er + GN * 4);                           // E
    int* srcs    = eidx + GE;                                     // E (CSR-ordered src)
    int* cursor  = srcs + GE;                                     // N
    // ---- contiguous zero region (single memset): deg | pooled
    int* deg       = cursor + GN;                                 // N
    unsigned* pooled = (unsigned*)(deg + GN);                     // B*512
    const size_t zero_bytes = (size_t)GN * 4 + (size_t)GB * 512 * 4;
    int* rs = (int*)(pooled + GB * 512);                          // N+1

    float* probs = (float*)d_out;
    float* aw = probs + GB * GC;  // E*4 floats

    hipMemsetAsync(deg, 0, zero_bytes, stream);
    prep_misc<<<1314, 256, 0, stream>>>(x, xb, W1, w1s, W2, w2s, dst, deg);
    exscan_kernel<<<1, 1024, 0, stream>>>(deg, rs, cursor);
    scatter_kernel<<<GE / 256, 256, 0, stream>>>(dst, src, cursor, eidx, srcs);

    // ---- layer 1
    gemm_logits<<<GN / 16, 256, 0, stream>>>(xb, w1s, al1, ar1, hb, el, er);
    gather_l1<<<GN / 4, 256, 0, stream>>>(rs, srcs, hb, el, er, b1, lng, lnb, h1b);

    // ---- layer 2
    gemm_logits<<<GN / 16, 256, 0, stream>>>(h1b, w2s, al2, ar2, hb, el, er);
    gather_l2<<<GN / 4, 256, 0, stream>>>(rs, srcs, eidx, hb, el, er, b2, gid, pooled, aw);

    // ---- head
    head_mlp<<<GB, 256, 0, stream>>>(pooled, Wa, ba, Wb, bb, g2, bt2, Wc, bc, probs);
}